// Round 8
// baseline (339.019 us; speedup 1.0000x reference)
//
#include <hip/hip_runtime.h>

#define NN 100000
#define NE 600000

typedef __attribute__((ext_vector_type(8))) short short8;   // 8 bf16 (4 VGPRs)
typedef __attribute__((ext_vector_type(4))) float f32x4;    // MFMA C/D frag

static __device__ __forceinline__ float bf2f_lo(unsigned int u) {
  union { unsigned int i; float f; } v;
  v.i = u << 16;
  return v.f;
}
static __device__ __forceinline__ float bf2f_hi(unsigned int u) {
  union { unsigned int i; float f; } v;
  v.i = u & 0xffff0000u;
  return v.f;
}
static __device__ __forceinline__ unsigned short f2bf(float f) {
  union { float f; unsigned int i; } v;
  v.f = f;
  unsigned int x = v.i;
  x += 0x7FFFu + ((x >> 16) & 1u);  // round-to-nearest-even
  return (unsigned short)(x >> 16);
}

static __device__ __forceinline__ void async_cp16(const unsigned short* g, unsigned short* l) {
  __builtin_amdgcn_global_load_lds(
      (const __attribute__((address_space(1))) unsigned int*)g,
      (__attribute__((address_space(3))) unsigned int*)l,
      16, 0, 0);
}

// ---------- fused prologue ----------
// blocks [0,3125): cast x fp32->bf16, 4 float4/thread (MLP)
// blocks [3125,3701): 6 weight transposes
// blocks [3701,4287): degree count, 4 edges/thread
__global__ __launch_bounds__(256) void k_prep(
    const float* __restrict__ x, unsigned short* __restrict__ xb,
    const float* __restrict__ W1l, const float* __restrict__ W1r,
    const float* __restrict__ W2l, const float* __restrict__ W2r,
    const float* __restrict__ W3l, const float* __restrict__ W3r,
    unsigned short* __restrict__ t1l, unsigned short* __restrict__ t1r,
    unsigned short* __restrict__ t2l, unsigned short* __restrict__ t2r,
    unsigned short* __restrict__ t3l, unsigned short* __restrict__ t3r,
    const int* __restrict__ dst, int* __restrict__ cnt) {
  const int bid = blockIdx.x;
  if (bid < 3125) {                       // 3,200,000 float4s, 1024 per block
    int base = bid * 1024 + threadIdx.x;
    const float4* xf = (const float4*)x;
    float4 f0 = xf[base];
    float4 f1 = xf[base + 256];
    float4 f2 = xf[base + 512];
    float4 f3 = xf[base + 768];
    ushort4* ob = (ushort4*)xb;
    ushort4 o0, o1, o2, o3;
    o0.x = f2bf(f0.x); o0.y = f2bf(f0.y); o0.z = f2bf(f0.z); o0.w = f2bf(f0.w);
    o1.x = f2bf(f1.x); o1.y = f2bf(f1.y); o1.z = f2bf(f1.z); o1.w = f2bf(f1.w);
    o2.x = f2bf(f2.x); o2.y = f2bf(f2.y); o2.z = f2bf(f2.z); o2.w = f2bf(f2.w);
    o3.x = f2bf(f3.x); o3.y = f2bf(f3.y); o3.z = f2bf(f3.z); o3.w = f2bf(f3.w);
    ob[base] = o0; ob[base + 256] = o1; ob[base + 512] = o2; ob[base + 768] = o3;
  } else if (bid < 3701) {                // 147456 transpose elems
    int i = (bid - 3125) * 256 + threadIdx.x;
    const float* W; unsigned short* T; int ks, N;
    if (i < 65536)        { if (i < 32768) { W = W1l; T = t1l; } else { W = W1r; T = t1r; i -= 32768; } ks = 7; N = 256; }
    else if (i < 131072)  { if (i < 98304) { W = W2l; T = t2l; i -= 65536; } else { W = W2r; T = t2r; i -= 98304; } ks = 8; N = 128; }
    else                  { if (i < 139264) { W = W3l; T = t3l; i -= 131072; } else { W = W3r; T = t3r; i -= 139264; } ks = 7; N = 64; }
    int K = 1 << ks;
    int n = i >> ks, k = i & (K - 1);
    T[i] = f2bf(W[(size_t)k * N + n]);
  } else {                                // degree count, 4 edges/thread
    int i = (bid - 3701) * 1024 + threadIdx.x;
    #pragma unroll
    for (int j = 0; j < 4; j++) {
      int e = i + j * 256;
      if (e < NE) atomicAdd(&cnt[dst[e]], 1);
    }
  }
}

// ---------- multi-block scan: per-block reduce ----------
__global__ __launch_bounds__(256) void k_red(const int* __restrict__ off, int* __restrict__ part, int n) {
  __shared__ int ws[4];
  const int tid = threadIdx.x, wid = tid >> 6, lane = tid & 63;
  int i = blockIdx.x * 1024 + tid * 4;
  int s = 0;
  #pragma unroll
  for (int j = 0; j < 4; j++) if (i + j < n) s += off[i + j];
  #pragma unroll
  for (int d = 32; d; d >>= 1) s += __shfl_xor(s, d);
  if (lane == 0) ws[wid] = s;
  __syncthreads();
  if (tid == 0) part[blockIdx.x] = ws[0] + ws[1] + ws[2] + ws[3];
}

// ---------- fused prefix + local scan + write (replaces k_scan1 + k_add) ----------
// Each block computes its own prefix = sum(part[j], j<blockIdx.x) with a masked reduce.
__global__ __launch_bounds__(256) void k_add2(int* __restrict__ off, int* __restrict__ cur,
                                              const int* __restrict__ part, int nb, int n) {
  __shared__ int wsum[4];
  __shared__ int sprefix;
  const int tid = threadIdx.x, wid = tid >> 6, lane = tid & 63;
  const int b = blockIdx.x;
  if (tid < 64) {                                  // nb <= 128
    int v0 = (lane < nb && lane < b) ? part[lane] : 0;
    int v1 = (64 + lane < nb && 64 + lane < b) ? part[64 + lane] : 0;
    int s = v0 + v1;
    #pragma unroll
    for (int d = 32; d; d >>= 1) s += __shfl_xor(s, d);
    if (lane == 0) sprefix = s;
  }
  int i = b * 1024 + tid * 4;
  int v0 = (i + 0 < n) ? off[i + 0] : 0;
  int v1 = (i + 1 < n) ? off[i + 1] : 0;
  int v2 = (i + 2 < n) ? off[i + 2] : 0;
  int v3 = (i + 3 < n) ? off[i + 3] : 0;
  int s = v0 + v1 + v2 + v3;
  int incl = s;
  #pragma unroll
  for (int d = 1; d < 64; d <<= 1) {
    int t = __shfl_up(incl, (unsigned)d);
    if (lane >= d) incl += t;
  }
  if (lane == 63) wsum[wid] = incl;
  __syncthreads();
  if (tid == 0) {
    int c = 0;
    #pragma unroll
    for (int w = 0; w < 4; w++) { int t = wsum[w]; wsum[w] = c; c += t; }
    if (b == gridDim.x - 1) off[n] = sprefix + c;  // total edge count
  }
  __syncthreads();
  int excl = sprefix + wsum[wid] + (incl - s);
  if (i + 0 < n) { off[i + 0] = excl; cur[i + 0] = excl; } excl += v0;
  if (i + 1 < n) { off[i + 1] = excl; cur[i + 1] = excl; } excl += v1;
  if (i + 2 < n) { off[i + 2] = excl; cur[i + 2] = excl; } excl += v2;
  if (i + 3 < n) { off[i + 3] = excl; cur[i + 3] = excl; } excl += v3;
}

// ---------- CSR bucket fill: 4 edges/thread ----------
__global__ __launch_bounds__(256) void k_fill(const int* __restrict__ src, const int* __restrict__ dst,
                                              int* __restrict__ cur, int* __restrict__ esrc) {
  int i = blockIdx.x * 1024 + threadIdx.x;
  #pragma unroll
  for (int j = 0; j < 4; j++) {
    int e = i + j * 256;
    if (e < NE) {
      int p = atomicAdd(&cur[dst[e]], 1);
      esrc[p] = src[e];
    }
  }
}

// ---------- gather-mean, C=128 rows: 4 nodes/wave, 16 lanes/node, uint4 loads, unroll-4 ----------
template <bool ADD>
__global__ __launch_bounds__(256) void k_gather4_128(const unsigned short* __restrict__ feat,
                                                     const unsigned short* __restrict__ t,
                                                     const int* __restrict__ off,
                                                     const int* __restrict__ esrc,
                                                     unsigned short* __restrict__ outp) {
  const int tid = threadIdx.x;
  const int sl = tid & 15;
  const int v = blockIdx.x * 16 + (tid >> 4);
  const int s0 = off[v], deg = off[v + 1] - s0;
  const int deg16 = deg < 16 ? deg : 16;
  int idx = (sl < deg16) ? esrc[s0 + sl] : 0;
  const uint4* fp = (const uint4*)feat;             // 16 uint4 per row

  float a0 = 0.f, a1 = 0.f, a2 = 0.f, a3 = 0.f, a4 = 0.f, a5 = 0.f, a6 = 0.f, a7 = 0.f;
  auto accum = [&](uint4 u) {
    a0 += bf2f_lo(u.x); a1 += bf2f_hi(u.x);
    a2 += bf2f_lo(u.y); a3 += bf2f_hi(u.y);
    a4 += bf2f_lo(u.z); a5 += bf2f_hi(u.z);
    a6 += bf2f_lo(u.w); a7 += bf2f_hi(u.w);
  };
  int e = 0;
  for (; e + 4 <= deg16; e += 4) {
    int i0 = __shfl(idx, e, 16), i1 = __shfl(idx, e + 1, 16);
    int i2 = __shfl(idx, e + 2, 16), i3 = __shfl(idx, e + 3, 16);
    uint4 u0 = fp[(size_t)i0 * 16 + sl];
    uint4 u1 = fp[(size_t)i1 * 16 + sl];
    uint4 u2 = fp[(size_t)i2 * 16 + sl];
    uint4 u3 = fp[(size_t)i3 * 16 + sl];
    accum(u0); accum(u1); accum(u2); accum(u3);
  }
  for (; e < deg16; e++) accum(fp[(size_t)__shfl(idx, e, 16) * 16 + sl]);
  for (; e < deg; e++) accum(fp[(size_t)esrc[s0 + e] * 16 + sl]);  // rare deg>16 tail

  float inv = 1.0f / (float)(deg > 1 ? deg : 1);
  float r0, r1, r2, r3, r4, r5, r6, r7;
  if (ADD) {
    uint4 tu = ((const uint4*)t)[(size_t)v * 16 + sl];
    r0 = fmaxf(a0 * inv + bf2f_lo(tu.x), 0.f); r1 = fmaxf(a1 * inv + bf2f_hi(tu.x), 0.f);
    r2 = fmaxf(a2 * inv + bf2f_lo(tu.y), 0.f); r3 = fmaxf(a3 * inv + bf2f_hi(tu.y), 0.f);
    r4 = fmaxf(a4 * inv + bf2f_lo(tu.z), 0.f); r5 = fmaxf(a5 * inv + bf2f_hi(tu.z), 0.f);
    r6 = fmaxf(a6 * inv + bf2f_lo(tu.w), 0.f); r7 = fmaxf(a7 * inv + bf2f_hi(tu.w), 0.f);
  } else {
    r0 = a0 * inv; r1 = a1 * inv; r2 = a2 * inv; r3 = a3 * inv;
    r4 = a4 * inv; r5 = a5 * inv; r6 = a6 * inv; r7 = a7 * inv;
  }
  uint4 o;
  o.x = (unsigned int)f2bf(r0) | ((unsigned int)f2bf(r1) << 16);
  o.y = (unsigned int)f2bf(r2) | ((unsigned int)f2bf(r3) << 16);
  o.z = (unsigned int)f2bf(r4) | ((unsigned int)f2bf(r5) << 16);
  o.w = (unsigned int)f2bf(r6) | ((unsigned int)f2bf(r7) << 16);
  ((uint4*)outp)[(size_t)v * 16 + sl] = o;
}

// ---------- L3 fused: out = log_softmax(mean(g[src]) + t), C=64 rows ----------
// 8 nodes/wave, 8 lanes/node, uint4 (16B) loads; softmax within 8-lane groups.
__global__ __launch_bounds__(256) void k_gather8_lsm(const unsigned short* __restrict__ g,
                                                     const unsigned short* __restrict__ t,
                                                     const int* __restrict__ off,
                                                     const int* __restrict__ esrc,
                                                     float* __restrict__ out) {
  const int tid = threadIdx.x;
  const int sl = tid & 7;
  const int v = blockIdx.x * 32 + (tid >> 3);
  const int s0 = off[v], deg = off[v + 1] - s0;
  const int deg8 = deg < 8 ? deg : 8;
  const int deg16 = deg < 16 ? deg : 16;
  int idxA = (sl < deg8) ? esrc[s0 + sl] : 0;
  int idxB = (sl + 8 < deg16) ? esrc[s0 + 8 + sl] : 0;
  const uint4* fp = (const uint4*)g;                // 8 uint4 per row

  float a0 = 0.f, a1 = 0.f, a2 = 0.f, a3 = 0.f, a4 = 0.f, a5 = 0.f, a6 = 0.f, a7 = 0.f;
  auto accum = [&](uint4 u) {
    a0 += bf2f_lo(u.x); a1 += bf2f_hi(u.x);
    a2 += bf2f_lo(u.y); a3 += bf2f_hi(u.y);
    a4 += bf2f_lo(u.z); a5 += bf2f_hi(u.z);
    a6 += bf2f_lo(u.w); a7 += bf2f_hi(u.w);
  };
  int e = 0;
  for (; e + 4 <= deg8; e += 4) {
    int i0 = __shfl(idxA, e, 8), i1 = __shfl(idxA, e + 1, 8);
    int i2 = __shfl(idxA, e + 2, 8), i3 = __shfl(idxA, e + 3, 8);
    uint4 u0 = fp[(size_t)i0 * 8 + sl];
    uint4 u1 = fp[(size_t)i1 * 8 + sl];
    uint4 u2 = fp[(size_t)i2 * 8 + sl];
    uint4 u3 = fp[(size_t)i3 * 8 + sl];
    accum(u0); accum(u1); accum(u2); accum(u3);
  }
  for (; e < deg8; e++) accum(fp[(size_t)__shfl(idxA, e, 8) * 8 + sl]);
  for (; e < deg16; e++) accum(fp[(size_t)__shfl(idxB, e - 8, 8) * 8 + sl]);
  for (; e < deg; e++) accum(fp[(size_t)esrc[s0 + e] * 8 + sl]);

  float inv = 1.0f / (float)(deg > 1 ? deg : 1);
  uint4 tu = ((const uint4*)t)[(size_t)v * 8 + sl];
  float v0 = a0 * inv + bf2f_lo(tu.x), v1 = a1 * inv + bf2f_hi(tu.x);
  float v2 = a2 * inv + bf2f_lo(tu.y), v3 = a3 * inv + bf2f_hi(tu.y);
  float v4 = a4 * inv + bf2f_lo(tu.z), v5 = a5 * inv + bf2f_hi(tu.z);
  float v6 = a6 * inv + bf2f_lo(tu.w), v7 = a7 * inv + bf2f_hi(tu.w);
  float m = fmaxf(fmaxf(fmaxf(v0, v1), fmaxf(v2, v3)), fmaxf(fmaxf(v4, v5), fmaxf(v6, v7)));
  #pragma unroll
  for (int s = 4; s; s >>= 1) m = fmaxf(m, __shfl_xor(m, s, 8));
  float sum = expf(v0 - m) + expf(v1 - m) + expf(v2 - m) + expf(v3 - m)
            + expf(v4 - m) + expf(v5 - m) + expf(v6 - m) + expf(v7 - m);
  #pragma unroll
  for (int s = 4; s; s >>= 1) sum += __shfl_xor(sum, s, 8);
  float ls = m + logf(sum);
  float4* op = (float4*)out;
  op[(size_t)v * 16 + sl * 2 + 0] = make_float4(v0 - ls, v1 - ls, v2 - ls, v3 - ls);
  op[(size_t)v * 16 + sl * 2 + 1] = make_float4(v4 - ls, v5 - ls, v6 - ls, v7 - ls);
}

// ---------- bf16 MFMA GEMM, BK=64, XOR-swizzled LDS, coalesced repack epilogue ----------
template <int BN, bool DUAL>
__global__ __launch_bounds__(BN * 2) void k_gmm(
    const unsigned short* __restrict__ A1, const unsigned short* __restrict__ Wt1,
    const unsigned short* __restrict__ A2, const unsigned short* __restrict__ Wt2,
    const float* __restrict__ bias, int M, int K, int N,
    unsigned short* __restrict__ out1, unsigned short* __restrict__ out2, int relu) {
  constexpr int NWAVE = BN / 32;          // 4 or 2
  constexpr int ACHUNKS = 16;             // 128 rows / 8 rows-per-chunk
  constexpr int BCHUNKS = BN / 8;
  constexpr int STR = BN + 8;             // repack slab row stride
  __shared__ unsigned short smem[128 * 64 + BN * 64];
  unsigned short* As = smem;
  unsigned short* Bs = smem + 128 * 64;
  const int t = threadIdx.x;
  const int w = t >> 6, lane = t & 63;
  const int quad = lane >> 4, l15 = lane & 15;
  const int wm = w & 1, wn = w >> 1;      // BN=64: wn==0
  const int m0 = blockIdx.x * 128;
  const int n0 = DUAL ? blockIdx.y * BN : 0;
  const int srow = lane >> 3;             // row in 8-row chunk
  const int sk = (((lane & 7) ^ (srow & 7)) * 8);  // swizzled source k-offset (elems)

  const unsigned short* Wt = DUAL ? Wt1 : (blockIdx.y ? Wt2 : Wt1);
  unsigned short* out = DUAL ? out1 : (blockIdx.y ? out2 : out1);
  const float* bs = DUAL ? bias : (blockIdx.y ? bias : nullptr);

  f32x4 acc[4][4];
  #pragma unroll
  for (int i = 0; i < 4; i++)
    #pragma unroll
    for (int j = 0; j < 4; j++) acc[i][j] = (f32x4){0.f, 0.f, 0.f, 0.f};

  const int nph = DUAL ? 2 : 1;
  for (int ph = 0; ph < nph; ph++) {
    const unsigned short* A = (DUAL && ph) ? A2 : A1;
    const unsigned short* W = (DUAL && ph) ? Wt2 : Wt;
    for (int k0 = 0; k0 < K; k0 += 64) {
      #pragma unroll
      for (int c = w; c < ACHUNKS; c += NWAVE) {
        int rg = m0 + c * 8 + srow;
        if (rg >= M) rg = M - 1;          // clamp; epilogue guards stores
        async_cp16(A + (size_t)rg * K + k0 + sk, As + c * 512);
      }
      #pragma unroll
      for (int c = w; c < BCHUNKS; c += NWAVE) {
        async_cp16(W + (size_t)(n0 + c * 8 + srow) * K + k0 + sk, Bs + c * 512);
      }
      __syncthreads();
      short8 af[2][4], bfr[2][4];
      #pragma unroll
      for (int kh = 0; kh < 2; kh++) {
        #pragma unroll
        for (int mt = 0; mt < 4; mt++) {
          int r = wm * 64 + mt * 16 + l15;
          int cc = (kh * 4 + quad) ^ (r & 7);
          af[kh][mt] = *(const short8*)&As[r * 64 + cc * 8];
        }
        #pragma unroll
        for (int nt = 0; nt < 4; nt++) {
          int r = wn * 64 + nt * 16 + l15;
          int cc = (kh * 4 + quad) ^ (r & 7);
          bfr[kh][nt] = *(const short8*)&Bs[r * 64 + cc * 8];
        }
      }
      #pragma unroll
      for (int kh = 0; kh < 2; kh++)
        #pragma unroll
        for (int mt = 0; mt < 4; mt++)
          #pragma unroll
          for (int nt = 0; nt < 4; nt++)
            acc[mt][nt] = __builtin_amdgcn_mfma_f32_16x16x32_bf16(af[kh][mt], bfr[kh][nt], acc[mt][nt], 0, 0, 0);
      __syncthreads();
    }
  }

  // epilogue: repack per-mt slab (32 rows x BN cols bf16) in LDS -> 16B coalesced stores
  float bia[4];
  #pragma unroll
  for (int nt = 0; nt < 4; nt++)
    bia[nt] = bs ? bs[n0 + wn * 64 + nt * 16 + l15] : 0.f;
  constexpr int CH_PER_ROW = BN / 8;
  constexpr int TOT_CH = 32 * CH_PER_ROW;
  for (int mt = 0; mt < 4; mt++) {
    __syncthreads();
    #pragma unroll
    for (int nt = 0; nt < 4; nt++) {
      int col = wn * 64 + nt * 16 + l15;
      #pragma unroll
      for (int r = 0; r < 4; r++) {
        float v = acc[mt][nt][r] + bia[nt];
        if (relu) v = fmaxf(v, 0.f);
        smem[(wm * 16 + quad * 4 + r) * STR + col] = f2bf(v);
      }
    }
    __syncthreads();
    #pragma unroll
    for (int c = t; c < TOT_CH; c += BN * 2) {
      int row = c / CH_PER_ROW, ofs = (c % CH_PER_ROW) * 8;
      int m = m0 + (row >> 4) * 64 + mt * 16 + (row & 15);
      if (m < M)
        *(short8*)(out + (size_t)m * N + n0 + ofs) = *(const short8*)&smem[row * STR + ofs];
    }
  }
}

extern "C" void kernel_launch(void* const* d_in, const int* in_sizes, int n_in,
                              void* d_out, int out_size, void* d_ws, size_t ws_size,
                              hipStream_t stream) {
  const float* x   = (const float*)d_in[0];
  const int*   ei  = (const int*)d_in[1];
  const float* W1l = (const float*)d_in[2];
  const float* W1r = (const float*)d_in[3];
  const float* b1  = (const float*)d_in[4];
  const float* W2l = (const float*)d_in[5];
  const float* W2r = (const float*)d_in[6];
  const float* b2  = (const float*)d_in[7];
  const float* W3l = (const float*)d_in[8];
  const float* W3r = (const float*)d_in[9];
  const float* b3  = (const float*)d_in[10];
  float* out = (float*)d_out;
  const int* src = ei;
  const int* dst = ei + NE;

  char* w = (char*)d_ws;
  auto alloc = [&](size_t bytes) {
    char* p = w;
    w += (bytes + 255) & ~(size_t)255;
    return p;
  };
  int* off  = (int*)alloc((NN + 1) * sizeof(int));
  int* cur  = (int*)alloc(NN * sizeof(int));
  int* part = (int*)alloc(256 * sizeof(int));
  int* esrc = (int*)alloc((size_t)NE * sizeof(int));
  unsigned short* xb = (unsigned short*)alloc((size_t)NN * 128 * 2);
  unsigned short* mb = (unsigned short*)alloc((size_t)NN * 128 * 2);  // L1 mean; aliased as g2
  unsigned short* h1 = (unsigned short*)alloc((size_t)NN * 256 * 2);  // aliased as g3|t3 later
  unsigned short* h2 = (unsigned short*)alloc((size_t)NN * 128 * 2);
  unsigned short* t2 = (unsigned short*)alloc((size_t)NN * 128 * 2);
  unsigned short* t1l = (unsigned short*)alloc(128 * 256 * 2);
  unsigned short* t1r = (unsigned short*)alloc(128 * 256 * 2);
  unsigned short* t2l = (unsigned short*)alloc(256 * 128 * 2);
  unsigned short* t2r = (unsigned short*)alloc(256 * 128 * 2);
  unsigned short* t3l = (unsigned short*)alloc(128 * 64 * 2);
  unsigned short* t3r = (unsigned short*)alloc(128 * 64 * 2);
  unsigned short* g2 = mb;                       // reuse: mb dead after L1 GEMM
  unsigned short* g3 = h1;                       // reuse: h1 dead after L2 GEMM
  unsigned short* t3 = h1 + (size_t)NN * 64;

  const int NB = (NN + 1023) / 1024;  // 98
  const int EB = (NE + 1023) / 1024;  // 586

  hipMemsetAsync(off, 0, (NN + 1) * sizeof(int), stream);
  // fused cast (MLP x4) + weight transpose + degree count (4 edges/thread)
  k_prep<<<3125 + 576 + EB, 256, 0, stream>>>(x, xb, W1l, W1r, W2l, W2r, W3l, W3r,
                                              t1l, t1r, t2l, t2r, t3l, t3r, dst, off);
  k_red<<<NB, 256, 0, stream>>>(off, part, NN);
  k_add2<<<NB, 256, 0, stream>>>(off, cur, part, NB, NN);
  k_fill<<<EB, 256, 0, stream>>>(src, dst, cur, esrc);

  const int MB = (NN + 127) / 128;  // 782
  const int GB16 = NN / 16;         // 6250
  const int GB32 = NN / 32;         // 3125
  // L1: h1 = relu(mean(xb)@W1l + xb@W1r + b1)
  k_gather4_128<false><<<GB16, 256, 0, stream>>>(xb, nullptr, off, esrc, mb);
  k_gmm<128, true><<<dim3(MB, 2), 256, 0, stream>>>(mb, t1l, xb, t1r, b1, NN, 128, 256, h1, nullptr, 1);
  // L2: g2 = h1@W2l ; t2 = h1@W2r + b2 ; h2 = relu(mean(g2[src]) + t2)
  k_gmm<128, false><<<dim3(MB, 2), 256, 0, stream>>>(h1, t2l, nullptr, t2r, b2, NN, 256, 128, g2, t2, 0);
  k_gather4_128<true><<<GB16, 256, 0, stream>>>(g2, t2, off, esrc, h2);
  // L3: g3 = h2@W3l ; t3 = h2@W3r + b3 ; out = log_softmax(mean(g3[src]) + t3)
  k_gmm<64, false><<<dim3(MB, 2), 128, 0, stream>>>(h2, t3l, nullptr, t3r, b3, NN, 128, 64, g3, t3, 0);
  k_gather8_lsm<<<GB32, 256, 0, stream>>>(g3, t3, off, esrc, out);
}

// Round 9
// 299.646 us; speedup vs baseline: 1.1314x; 1.1314x over previous
//
#include <hip/hip_runtime.h>

#define NN 100000
#define NE 600000
#define SPILL_CAP 8192

typedef __attribute__((ext_vector_type(8))) short short8;   // 8 bf16 (4 VGPRs)
typedef __attribute__((ext_vector_type(4))) float f32x4;    // MFMA C/D frag

static __device__ __forceinline__ float bf2f_lo(unsigned int u) {
  union { unsigned int i; float f; } v;
  v.i = u << 16;
  return v.f;
}
static __device__ __forceinline__ float bf2f_hi(unsigned int u) {
  union { unsigned int i; float f; } v;
  v.i = u & 0xffff0000u;
  return v.f;
}
static __device__ __forceinline__ unsigned short f2bf(float f) {
  union { float f; unsigned int i; } v;
  v.f = f;
  unsigned int x = v.i;
  x += 0x7FFFu + ((x >> 16) & 1u);  // round-to-nearest-even
  return (unsigned short)(x >> 16);
}

static __device__ __forceinline__ void async_cp16(const unsigned short* g, unsigned short* l) {
  __builtin_amdgcn_global_load_lds(
      (const __attribute__((address_space(1))) unsigned int*)g,
      (__attribute__((address_space(3))) unsigned int*)l,
      16, 0, 0);
}

// ---------- fused prologue ----------
// blocks [0,2344): slot-CSR fill (1 edge/thread, atomic count+place in ONE pass)
// blocks [2344,5469): cast x fp32->bf16, 4 float4/thread
// blocks [5469,6045): 6 weight transposes
__global__ __launch_bounds__(256) void k_prep(
    const float* __restrict__ x, unsigned short* __restrict__ xb,
    const float* __restrict__ W1l, const float* __restrict__ W1r,
    const float* __restrict__ W2l, const float* __restrict__ W2r,
    const float* __restrict__ W3l, const float* __restrict__ W3r,
    unsigned short* __restrict__ t1l, unsigned short* __restrict__ t1r,
    unsigned short* __restrict__ t2l, unsigned short* __restrict__ t2r,
    unsigned short* __restrict__ t3l, unsigned short* __restrict__ t3r,
    const int* __restrict__ src, const int* __restrict__ dst,
    int* __restrict__ cnt, int* __restrict__ S,
    int* __restrict__ spillc, int* __restrict__ spill) {
  const int bid = blockIdx.x;
  if (bid < 2344) {                       // CSR slot fill (latency-bound: max TLP)
    int e = bid * 256 + threadIdx.x;
    if (e < NE) {
      int d = dst[e], s = src[e];
      int p = atomicAdd(&cnt[d], 1);
      if (p < 32) S[d * 32 + p] = s;
      else {
        int q = atomicAdd(spillc, 1);
        if (q < SPILL_CAP) { spill[2 * q] = d; spill[2 * q + 1] = s; }
      }
    }
  } else if (bid < 5469) {                // cast: 3,200,000 float4s, 1024/block
    int base = (bid - 2344) * 1024 + threadIdx.x;
    const float4* xf = (const float4*)x;
    float4 f0 = xf[base];
    float4 f1 = xf[base + 256];
    float4 f2 = xf[base + 512];
    float4 f3 = xf[base + 768];
    ushort4* ob = (ushort4*)xb;
    ushort4 o0, o1, o2, o3;
    o0.x = f2bf(f0.x); o0.y = f2bf(f0.y); o0.z = f2bf(f0.z); o0.w = f2bf(f0.w);
    o1.x = f2bf(f1.x); o1.y = f2bf(f1.y); o1.z = f2bf(f1.z); o1.w = f2bf(f1.w);
    o2.x = f2bf(f2.x); o2.y = f2bf(f2.y); o2.z = f2bf(f2.z); o2.w = f2bf(f2.w);
    o3.x = f2bf(f3.x); o3.y = f2bf(f3.y); o3.z = f2bf(f3.z); o3.w = f2bf(f3.w);
    ob[base] = o0; ob[base + 256] = o1; ob[base + 512] = o2; ob[base + 768] = o3;
  } else {                                // 147456 transpose elems
    int i = (bid - 5469) * 256 + threadIdx.x;
    const float* W; unsigned short* T; int ks, N;
    if (i < 65536)        { if (i < 32768) { W = W1l; T = t1l; } else { W = W1r; T = t1r; i -= 32768; } ks = 7; N = 256; }
    else if (i < 131072)  { if (i < 98304) { W = W2l; T = t2l; i -= 65536; } else { W = W2r; T = t2r; i -= 98304; } ks = 8; N = 128; }
    else                  { if (i < 139264) { W = W3l; T = t3l; i -= 131072; } else { W = W3r; T = t3r; i -= 139264; } ks = 7; N = 64; }
    int K = 1 << ks;
    int n = i >> ks, k = i & (K - 1);
    T[i] = f2bf(W[(size_t)k * N + n]);
  }
}

// ---------- gather-mean, C=128 rows: 4 nodes/wave, 16 lanes/node, uint4 loads ----------
template <bool ADD>
__global__ __launch_bounds__(256) void k_gather4_128(const unsigned short* __restrict__ feat,
                                                     const unsigned short* __restrict__ t,
                                                     const int* __restrict__ cnt,
                                                     const int* __restrict__ S,
                                                     const int* __restrict__ spillc,
                                                     const int* __restrict__ spill,
                                                     unsigned short* __restrict__ outp) {
  const int tid = threadIdx.x;
  const int sl = tid & 15;
  const int v = blockIdx.x * 16 + (tid >> 4);
  const int deg = cnt[v];
  const int cap = deg < 16 ? deg : 16;
  const int dcap = deg < 32 ? deg : 32;
  int idx = (sl < cap) ? S[v * 32 + sl] : 0;
  const uint4* fp = (const uint4*)feat;             // 16 uint4 per row

  float a0 = 0.f, a1 = 0.f, a2 = 0.f, a3 = 0.f, a4 = 0.f, a5 = 0.f, a6 = 0.f, a7 = 0.f;
  auto accum = [&](uint4 u) {
    a0 += bf2f_lo(u.x); a1 += bf2f_hi(u.x);
    a2 += bf2f_lo(u.y); a3 += bf2f_hi(u.y);
    a4 += bf2f_lo(u.z); a5 += bf2f_hi(u.z);
    a6 += bf2f_lo(u.w); a7 += bf2f_hi(u.w);
  };
  int e = 0;
  for (; e + 4 <= cap; e += 4) {
    int i0 = __shfl(idx, e, 16), i1 = __shfl(idx, e + 1, 16);
    int i2 = __shfl(idx, e + 2, 16), i3 = __shfl(idx, e + 3, 16);
    uint4 u0 = fp[(size_t)i0 * 16 + sl];
    uint4 u1 = fp[(size_t)i1 * 16 + sl];
    uint4 u2 = fp[(size_t)i2 * 16 + sl];
    uint4 u3 = fp[(size_t)i3 * 16 + sl];
    accum(u0); accum(u1); accum(u2); accum(u3);
  }
  for (; e < cap; e++) accum(fp[(size_t)__shfl(idx, e, 16) * 16 + sl]);
  for (; e < dcap; e++) accum(fp[(size_t)S[v * 32 + e] * 16 + sl]);  // deg in (16,32]
  if (deg > 32) {                                    // never in practice
    int L = *spillc; if (L > SPILL_CAP) L = SPILL_CAP;
    for (int i2 = 0; i2 < L; i2++)
      if (spill[2 * i2] == v) accum(fp[(size_t)spill[2 * i2 + 1] * 16 + sl]);
  }

  float inv = 1.0f / (float)(deg > 1 ? deg : 1);
  float r0, r1, r2, r3, r4, r5, r6, r7;
  if (ADD) {
    uint4 tu = ((const uint4*)t)[(size_t)v * 16 + sl];
    r0 = fmaxf(a0 * inv + bf2f_lo(tu.x), 0.f); r1 = fmaxf(a1 * inv + bf2f_hi(tu.x), 0.f);
    r2 = fmaxf(a2 * inv + bf2f_lo(tu.y), 0.f); r3 = fmaxf(a3 * inv + bf2f_hi(tu.y), 0.f);
    r4 = fmaxf(a4 * inv + bf2f_lo(tu.z), 0.f); r5 = fmaxf(a5 * inv + bf2f_hi(tu.z), 0.f);
    r6 = fmaxf(a6 * inv + bf2f_lo(tu.w), 0.f); r7 = fmaxf(a7 * inv + bf2f_hi(tu.w), 0.f);
  } else {
    r0 = a0 * inv; r1 = a1 * inv; r2 = a2 * inv; r3 = a3 * inv;
    r4 = a4 * inv; r5 = a5 * inv; r6 = a6 * inv; r7 = a7 * inv;
  }
  uint4 o;
  o.x = (unsigned int)f2bf(r0) | ((unsigned int)f2bf(r1) << 16);
  o.y = (unsigned int)f2bf(r2) | ((unsigned int)f2bf(r3) << 16);
  o.z = (unsigned int)f2bf(r4) | ((unsigned int)f2bf(r5) << 16);
  o.w = (unsigned int)f2bf(r6) | ((unsigned int)f2bf(r7) << 16);
  ((uint4*)outp)[(size_t)v * 16 + sl] = o;
}

// ---------- L3 fused: out = log_softmax(mean(g[src]) + t), C=64 rows ----------
__global__ __launch_bounds__(256) void k_gather8_lsm(const unsigned short* __restrict__ g,
                                                     const unsigned short* __restrict__ t,
                                                     const int* __restrict__ cnt,
                                                     const int* __restrict__ S,
                                                     const int* __restrict__ spillc,
                                                     const int* __restrict__ spill,
                                                     float* __restrict__ out) {
  const int tid = threadIdx.x;
  const int sl = tid & 7;
  const int v = blockIdx.x * 32 + (tid >> 3);
  const int deg = cnt[v];
  const int cap8 = deg < 8 ? deg : 8;
  const int cap16 = deg < 16 ? deg : 16;
  const int dcap = deg < 32 ? deg : 32;
  int idxA = (sl < cap8) ? S[v * 32 + sl] : 0;
  int idxB = (8 + sl < cap16) ? S[v * 32 + 8 + sl] : 0;
  const uint4* fp = (const uint4*)g;                // 8 uint4 per row

  float a0 = 0.f, a1 = 0.f, a2 = 0.f, a3 = 0.f, a4 = 0.f, a5 = 0.f, a6 = 0.f, a7 = 0.f;
  auto accum = [&](uint4 u) {
    a0 += bf2f_lo(u.x); a1 += bf2f_hi(u.x);
    a2 += bf2f_lo(u.y); a3 += bf2f_hi(u.y);
    a4 += bf2f_lo(u.z); a5 += bf2f_hi(u.z);
    a6 += bf2f_lo(u.w); a7 += bf2f_hi(u.w);
  };
  int e = 0;
  for (; e + 4 <= cap8; e += 4) {
    int i0 = __shfl(idxA, e, 8), i1 = __shfl(idxA, e + 1, 8);
    int i2 = __shfl(idxA, e + 2, 8), i3 = __shfl(idxA, e + 3, 8);
    uint4 u0 = fp[(size_t)i0 * 8 + sl];
    uint4 u1 = fp[(size_t)i1 * 8 + sl];
    uint4 u2 = fp[(size_t)i2 * 8 + sl];
    uint4 u3 = fp[(size_t)i3 * 8 + sl];
    accum(u0); accum(u1); accum(u2); accum(u3);
  }
  for (; e < cap8; e++) accum(fp[(size_t)__shfl(idxA, e, 8) * 8 + sl]);
  for (; e < cap16; e++) accum(fp[(size_t)__shfl(idxB, e - 8, 8) * 8 + sl]);
  for (; e < dcap; e++) accum(fp[(size_t)S[v * 32 + e] * 8 + sl]);
  if (deg > 32) {                                    // never in practice
    int L = *spillc; if (L > SPILL_CAP) L = SPILL_CAP;
    for (int i2 = 0; i2 < L; i2++)
      if (spill[2 * i2] == v) accum(fp[(size_t)spill[2 * i2 + 1] * 8 + sl]);
  }

  float inv = 1.0f / (float)(deg > 1 ? deg : 1);
  uint4 tu = ((const uint4*)t)[(size_t)v * 8 + sl];
  float v0 = a0 * inv + bf2f_lo(tu.x), v1 = a1 * inv + bf2f_hi(tu.x);
  float v2 = a2 * inv + bf2f_lo(tu.y), v3 = a3 * inv + bf2f_hi(tu.y);
  float v4 = a4 * inv + bf2f_lo(tu.z), v5 = a5 * inv + bf2f_hi(tu.z);
  float v6 = a6 * inv + bf2f_lo(tu.w), v7 = a7 * inv + bf2f_hi(tu.w);
  float m = fmaxf(fmaxf(fmaxf(v0, v1), fmaxf(v2, v3)), fmaxf(fmaxf(v4, v5), fmaxf(v6, v7)));
  #pragma unroll
  for (int s = 4; s; s >>= 1) m = fmaxf(m, __shfl_xor(m, s, 8));
  float sum = expf(v0 - m) + expf(v1 - m) + expf(v2 - m) + expf(v3 - m)
            + expf(v4 - m) + expf(v5 - m) + expf(v6 - m) + expf(v7 - m);
  #pragma unroll
  for (int s = 4; s; s >>= 1) sum += __shfl_xor(sum, s, 8);
  float ls = m + logf(sum);
  float4* op = (float4*)out;
  op[(size_t)v * 16 + sl * 2 + 0] = make_float4(v0 - ls, v1 - ls, v2 - ls, v3 - ls);
  op[(size_t)v * 16 + sl * 2 + 1] = make_float4(v4 - ls, v5 - ls, v6 - ls, v7 - ls);
}

// ---------- bf16 MFMA GEMM, BK=64, XOR-swizzled LDS, coalesced repack epilogue ----------
template <int BN, bool DUAL>
__global__ __launch_bounds__(BN * 2) void k_gmm(
    const unsigned short* __restrict__ A1, const unsigned short* __restrict__ Wt1,
    const unsigned short* __restrict__ A2, const unsigned short* __restrict__ Wt2,
    const float* __restrict__ bias, int M, int K, int N,
    unsigned short* __restrict__ out1, unsigned short* __restrict__ out2, int relu) {
  constexpr int NWAVE = BN / 32;          // 4 or 2
  constexpr int ACHUNKS = 16;             // 128 rows / 8 rows-per-chunk
  constexpr int BCHUNKS = BN / 8;
  constexpr int STR = BN + 8;             // repack slab row stride
  __shared__ unsigned short smem[128 * 64 + BN * 64];
  unsigned short* As = smem;
  unsigned short* Bs = smem + 128 * 64;
  const int t = threadIdx.x;
  const int w = t >> 6, lane = t & 63;
  const int quad = lane >> 4, l15 = lane & 15;
  const int wm = w & 1, wn = w >> 1;      // BN=64: wn==0
  const int m0 = blockIdx.x * 128;
  const int n0 = DUAL ? blockIdx.y * BN : 0;
  const int srow = lane >> 3;             // row in 8-row chunk
  const int sk = (((lane & 7) ^ (srow & 7)) * 8);  // swizzled source k-offset (elems)

  const unsigned short* Wt = DUAL ? Wt1 : (blockIdx.y ? Wt2 : Wt1);
  unsigned short* out = DUAL ? out1 : (blockIdx.y ? out2 : out1);
  const float* bs = DUAL ? bias : (blockIdx.y ? bias : nullptr);

  f32x4 acc[4][4];
  #pragma unroll
  for (int i = 0; i < 4; i++)
    #pragma unroll
    for (int j = 0; j < 4; j++) acc[i][j] = (f32x4){0.f, 0.f, 0.f, 0.f};

  const int nph = DUAL ? 2 : 1;
  for (int ph = 0; ph < nph; ph++) {
    const unsigned short* A = (DUAL && ph) ? A2 : A1;
    const unsigned short* W = (DUAL && ph) ? Wt2 : Wt;
    for (int k0 = 0; k0 < K; k0 += 64) {
      #pragma unroll
      for (int c = w; c < ACHUNKS; c += NWAVE) {
        int rg = m0 + c * 8 + srow;
        if (rg >= M) rg = M - 1;          // clamp; epilogue guards stores
        async_cp16(A + (size_t)rg * K + k0 + sk, As + c * 512);
      }
      #pragma unroll
      for (int c = w; c < BCHUNKS; c += NWAVE) {
        async_cp16(W + (size_t)(n0 + c * 8 + srow) * K + k0 + sk, Bs + c * 512);
      }
      __syncthreads();
      short8 af[2][4], bfr[2][4];
      #pragma unroll
      for (int kh = 0; kh < 2; kh++) {
        #pragma unroll
        for (int mt = 0; mt < 4; mt++) {
          int r = wm * 64 + mt * 16 + l15;
          int cc = (kh * 4 + quad) ^ (r & 7);
          af[kh][mt] = *(const short8*)&As[r * 64 + cc * 8];
        }
        #pragma unroll
        for (int nt = 0; nt < 4; nt++) {
          int r = wn * 64 + nt * 16 + l15;
          int cc = (kh * 4 + quad) ^ (r & 7);
          bfr[kh][nt] = *(const short8*)&Bs[r * 64 + cc * 8];
        }
      }
      #pragma unroll
      for (int kh = 0; kh < 2; kh++)
        #pragma unroll
        for (int mt = 0; mt < 4; mt++)
          #pragma unroll
          for (int nt = 0; nt < 4; nt++)
            acc[mt][nt] = __builtin_amdgcn_mfma_f32_16x16x32_bf16(af[kh][mt], bfr[kh][nt], acc[mt][nt], 0, 0, 0);
      __syncthreads();
    }
  }

  // epilogue: repack per-mt slab (32 rows x BN cols bf16) in LDS -> 16B coalesced stores
  float bia[4];
  #pragma unroll
  for (int nt = 0; nt < 4; nt++)
    bia[nt] = bs ? bs[n0 + wn * 64 + nt * 16 + l15] : 0.f;
  constexpr int CH_PER_ROW = BN / 8;
  constexpr int TOT_CH = 32 * CH_PER_ROW;
  for (int mt = 0; mt < 4; mt++) {
    __syncthreads();
    #pragma unroll
    for (int nt = 0; nt < 4; nt++) {
      int col = wn * 64 + nt * 16 + l15;
      #pragma unroll
      for (int r = 0; r < 4; r++) {
        float v = acc[mt][nt][r] + bia[nt];
        if (relu) v = fmaxf(v, 0.f);
        smem[(wm * 16 + quad * 4 + r) * STR + col] = f2bf(v);
      }
    }
    __syncthreads();
    #pragma unroll
    for (int c = t; c < TOT_CH; c += BN * 2) {
      int row = c / CH_PER_ROW, ofs = (c % CH_PER_ROW) * 8;
      int m = m0 + (row >> 4) * 64 + mt * 16 + (row & 15);
      if (m < M)
        *(short8*)(out + (size_t)m * N + n0 + ofs) = *(const short8*)&smem[row * STR + ofs];
    }
  }
}

extern "C" void kernel_launch(void* const* d_in, const int* in_sizes, int n_in,
                              void* d_out, int out_size, void* d_ws, size_t ws_size,
                              hipStream_t stream) {
  const float* x   = (const float*)d_in[0];
  const int*   ei  = (const int*)d_in[1];
  const float* W1l = (const float*)d_in[2];
  const float* W1r = (const float*)d_in[3];
  const float* b1  = (const float*)d_in[4];
  const float* W2l = (const float*)d_in[5];
  const float* W2r = (const float*)d_in[6];
  const float* b2  = (const float*)d_in[7];
  const float* W3l = (const float*)d_in[8];
  const float* W3r = (const float*)d_in[9];
  const float* b3  = (const float*)d_in[10];
  float* out = (float*)d_out;
  const int* src = ei;
  const int* dst = ei + NE;

  char* w = (char*)d_ws;
  auto alloc = [&](size_t bytes) {
    char* p = w;
    w += (bytes + 255) & ~(size_t)255;
    return p;
  };
  int* cnt    = (int*)alloc((NN + 1) * sizeof(int));  // cnt[NN] + spillc at [NN]
  int* spillc = cnt + NN;
  int* S      = (int*)alloc((size_t)NN * 32 * sizeof(int));
  int* spill  = (int*)alloc(2 * SPILL_CAP * sizeof(int));
  unsigned short* xb = (unsigned short*)alloc((size_t)NN * 128 * 2);
  unsigned short* mb = (unsigned short*)alloc((size_t)NN * 128 * 2);  // L1 mean; aliased as g2
  unsigned short* h1 = (unsigned short*)alloc((size_t)NN * 256 * 2);  // aliased as g3|t3 later
  unsigned short* h2 = (unsigned short*)alloc((size_t)NN * 128 * 2);
  unsigned short* t2 = (unsigned short*)alloc((size_t)NN * 128 * 2);
  unsigned short* t1l = (unsigned short*)alloc(128 * 256 * 2);
  unsigned short* t1r = (unsigned short*)alloc(128 * 256 * 2);
  unsigned short* t2l = (unsigned short*)alloc(256 * 128 * 2);
  unsigned short* t2r = (unsigned short*)alloc(256 * 128 * 2);
  unsigned short* t3l = (unsigned short*)alloc(128 * 64 * 2);
  unsigned short* t3r = (unsigned short*)alloc(128 * 64 * 2);
  unsigned short* g2 = mb;                       // reuse: mb dead after L1 GEMM
  unsigned short* g3 = h1;                       // reuse: h1 dead after L2 GEMM
  unsigned short* t3 = h1 + (size_t)NN * 64;

  hipMemsetAsync(cnt, 0, (NN + 1) * sizeof(int), stream);
  // fused slot-CSR fill + cast + weight transpose (one dispatch, sections overlap)
  k_prep<<<6045, 256, 0, stream>>>(x, xb, W1l, W1r, W2l, W2r, W3l, W3r,
                                   t1l, t1r, t2l, t2r, t3l, t3r,
                                   src, dst, cnt, S, spillc, spill);

  const int MB = (NN + 127) / 128;  // 782
  const int GB16 = NN / 16;         // 6250
  const int GB32 = NN / 32;         // 3125
  // L1: h1 = relu(mean(xb)@W1l + xb@W1r + b1)
  k_gather4_128<false><<<GB16, 256, 0, stream>>>(xb, nullptr, cnt, S, spillc, spill, mb);
  k_gmm<128, true><<<dim3(MB, 2), 256, 0, stream>>>(mb, t1l, xb, t1r, b1, NN, 128, 256, h1, nullptr, 1);
  // L2: g2 = h1@W2l ; t2 = h1@W2r + b2 ; h2 = relu(mean(g2[src]) + t2)
  k_gmm<128, false><<<dim3(MB, 2), 256, 0, stream>>>(h1, t2l, nullptr, t2r, b2, NN, 256, 128, g2, t2, 0);
  k_gather4_128<true><<<GB16, 256, 0, stream>>>(g2, t2, cnt, S, spillc, spill, h2);
  // L3: g3 = h2@W3l ; t3 = h2@W3r + b3 ; out = log_softmax(mean(g3[src]) + t3)
  k_gmm<64, false><<<dim3(MB, 2), 128, 0, stream>>>(h2, t3l, nullptr, t3r, b3, NN, 128, 64, g3, t3, 0);
  k_gather8_lsm<<<GB32, 256, 0, stream>>>(g3, t3, cnt, S, spillc, spill, out);
}

// Round 10
// 298.769 us; speedup vs baseline: 1.1347x; 1.0029x over previous
//
#include <hip/hip_runtime.h>

#define NN 100000
#define NE 600000
#define SPILL_CAP 8192

typedef __attribute__((ext_vector_type(8))) short short8;   // 8 bf16 (4 VGPRs)
typedef __attribute__((ext_vector_type(4))) float f32x4;    // MFMA C/D frag

static __device__ __forceinline__ float bf2f_lo(unsigned int u) {
  union { unsigned int i; float f; } v;
  v.i = u << 16;
  return v.f;
}
static __device__ __forceinline__ float bf2f_hi(unsigned int u) {
  union { unsigned int i; float f; } v;
  v.i = u & 0xffff0000u;
  return v.f;
}
static __device__ __forceinline__ unsigned short f2bf(float f) {
  union { float f; unsigned int i; } v;
  v.f = f;
  unsigned int x = v.i;
  x += 0x7FFFu + ((x >> 16) & 1u);  // round-to-nearest-even
  return (unsigned short)(x >> 16);
}

static __device__ __forceinline__ void async_cp16(const unsigned short* g, unsigned short* l) {
  __builtin_amdgcn_global_load_lds(
      (const __attribute__((address_space(1))) unsigned int*)g,
      (__attribute__((address_space(3))) unsigned int*)l,
      16, 0, 0);
}

// ---------- fused prologue ----------
// blocks [0,2344): slot-CSR fill (1 edge/thread, atomic count+place in ONE pass)
// blocks [2344,5469): cast x fp32->bf16, 4 float4/thread
// blocks [5469,6045): 6 weight transposes
__global__ __launch_bounds__(256) void k_prep(
    const float* __restrict__ x, unsigned short* __restrict__ xb,
    const float* __restrict__ W1l, const float* __restrict__ W1r,
    const float* __restrict__ W2l, const float* __restrict__ W2r,
    const float* __restrict__ W3l, const float* __restrict__ W3r,
    unsigned short* __restrict__ t1l, unsigned short* __restrict__ t1r,
    unsigned short* __restrict__ t2l, unsigned short* __restrict__ t2r,
    unsigned short* __restrict__ t3l, unsigned short* __restrict__ t3r,
    const int* __restrict__ src, const int* __restrict__ dst,
    int* __restrict__ cnt, int* __restrict__ S,
    int* __restrict__ spillc, int* __restrict__ spill) {
  const int bid = blockIdx.x;
  if (bid < 2344) {                       // CSR slot fill (latency-bound: max TLP)
    int e = bid * 256 + threadIdx.x;
    if (e < NE) {
      int d = dst[e], s = src[e];
      int p = atomicAdd(&cnt[d], 1);
      if (p < 32) S[d * 32 + p] = s;
      else {
        int q = atomicAdd(spillc, 1);
        if (q < SPILL_CAP) { spill[2 * q] = d; spill[2 * q + 1] = s; }
      }
    }
  } else if (bid < 5469) {                // cast: 3,200,000 float4s, 1024/block
    int base = (bid - 2344) * 1024 + threadIdx.x;
    const float4* xf = (const float4*)x;
    float4 f0 = xf[base];
    float4 f1 = xf[base + 256];
    float4 f2 = xf[base + 512];
    float4 f3 = xf[base + 768];
    ushort4* ob = (ushort4*)xb;
    ushort4 o0, o1, o2, o3;
    o0.x = f2bf(f0.x); o0.y = f2bf(f0.y); o0.z = f2bf(f0.z); o0.w = f2bf(f0.w);
    o1.x = f2bf(f1.x); o1.y = f2bf(f1.y); o1.z = f2bf(f1.z); o1.w = f2bf(f1.w);
    o2.x = f2bf(f2.x); o2.y = f2bf(f2.y); o2.z = f2bf(f2.z); o2.w = f2bf(f2.w);
    o3.x = f2bf(f3.x); o3.y = f2bf(f3.y); o3.z = f2bf(f3.z); o3.w = f2bf(f3.w);
    ob[base] = o0; ob[base + 256] = o1; ob[base + 512] = o2; ob[base + 768] = o3;
  } else {                                // 147456 transpose elems
    int i = (bid - 5469) * 256 + threadIdx.x;
    const float* W; unsigned short* T; int ks, N;
    if (i < 65536)        { if (i < 32768) { W = W1l; T = t1l; } else { W = W1r; T = t1r; i -= 32768; } ks = 7; N = 256; }
    else if (i < 131072)  { if (i < 98304) { W = W2l; T = t2l; i -= 65536; } else { W = W2r; T = t2r; i -= 98304; } ks = 8; N = 128; }
    else                  { if (i < 139264) { W = W3l; T = t3l; i -= 131072; } else { W = W3r; T = t3r; i -= 139264; } ks = 7; N = 64; }
    int K = 1 << ks;
    int n = i >> ks, k = i & (K - 1);
    T[i] = f2bf(W[(size_t)k * N + n]);
  }
}

// ---------- gather-mean, C=128 rows: 4 nodes/wave, 16 lanes/node ----------
// Fixed predicated batches of 8 independent uint4 loads (no serial tail).
template <bool ADD>
__global__ __launch_bounds__(256) void k_gather4_128(const unsigned short* __restrict__ feat,
                                                     const unsigned short* __restrict__ t,
                                                     const int* __restrict__ cnt,
                                                     const int* __restrict__ S,
                                                     const int* __restrict__ spillc,
                                                     const int* __restrict__ spill,
                                                     unsigned short* __restrict__ outp) {
  const int tid = threadIdx.x;
  const int sl = tid & 15;
  const int v = blockIdx.x * 16 + (tid >> 4);
  const int deg = cnt[v];
  const int cap = deg < 16 ? deg : 16;
  const int dcap = deg < 32 ? deg : 32;
  int idx = (sl < cap) ? S[v * 32 + sl] : 0;
  const uint4* fp = (const uint4*)feat;             // 16 uint4 per row

  float a0 = 0.f, a1 = 0.f, a2 = 0.f, a3 = 0.f, a4 = 0.f, a5 = 0.f, a6 = 0.f, a7 = 0.f;
  auto accum = [&](uint4 u) {
    a0 += bf2f_lo(u.x); a1 += bf2f_hi(u.x);
    a2 += bf2f_lo(u.y); a3 += bf2f_hi(u.y);
    a4 += bf2f_lo(u.z); a5 += bf2f_hi(u.z);
    a6 += bf2f_lo(u.w); a7 += bf2f_hi(u.w);
  };
  {
    uint4 u[8];
    #pragma unroll
    for (int e = 0; e < 8; e++) {
      int ie = __shfl(idx, e, 16);
      u[e] = fp[(size_t)ie * 16 + sl];
    }
    #pragma unroll
    for (int e = 0; e < 8; e++) {
      if (e >= deg) { u[e].x = 0; u[e].y = 0; u[e].z = 0; u[e].w = 0; }
      accum(u[e]);
    }
  }
  if (deg > 8) {
    uint4 u[8];
    #pragma unroll
    for (int e = 0; e < 8; e++) {
      int ie = __shfl(idx, 8 + e, 16);
      u[e] = fp[(size_t)ie * 16 + sl];
    }
    #pragma unroll
    for (int e = 0; e < 8; e++) {
      if (8 + e >= deg) { u[e].x = 0; u[e].y = 0; u[e].z = 0; u[e].w = 0; }
      accum(u[e]);
    }
  }
  for (int e = 16; e < dcap; e++) accum(fp[(size_t)S[v * 32 + e] * 16 + sl]);  // deg in (16,32]
  if (deg > 32) {                                    // never in practice
    int L = *spillc; if (L > SPILL_CAP) L = SPILL_CAP;
    for (int i2 = 0; i2 < L; i2++)
      if (spill[2 * i2] == v) accum(fp[(size_t)spill[2 * i2 + 1] * 16 + sl]);
  }

  float inv = 1.0f / (float)(deg > 1 ? deg : 1);
  float r0, r1, r2, r3, r4, r5, r6, r7;
  if (ADD) {
    uint4 tu = ((const uint4*)t)[(size_t)v * 16 + sl];
    r0 = fmaxf(a0 * inv + bf2f_lo(tu.x), 0.f); r1 = fmaxf(a1 * inv + bf2f_hi(tu.x), 0.f);
    r2 = fmaxf(a2 * inv + bf2f_lo(tu.y), 0.f); r3 = fmaxf(a3 * inv + bf2f_hi(tu.y), 0.f);
    r4 = fmaxf(a4 * inv + bf2f_lo(tu.z), 0.f); r5 = fmaxf(a5 * inv + bf2f_hi(tu.z), 0.f);
    r6 = fmaxf(a6 * inv + bf2f_lo(tu.w), 0.f); r7 = fmaxf(a7 * inv + bf2f_hi(tu.w), 0.f);
  } else {
    r0 = a0 * inv; r1 = a1 * inv; r2 = a2 * inv; r3 = a3 * inv;
    r4 = a4 * inv; r5 = a5 * inv; r6 = a6 * inv; r7 = a7 * inv;
  }
  uint4 o;
  o.x = (unsigned int)f2bf(r0) | ((unsigned int)f2bf(r1) << 16);
  o.y = (unsigned int)f2bf(r2) | ((unsigned int)f2bf(r3) << 16);
  o.z = (unsigned int)f2bf(r4) | ((unsigned int)f2bf(r5) << 16);
  o.w = (unsigned int)f2bf(r6) | ((unsigned int)f2bf(r7) << 16);
  ((uint4*)outp)[(size_t)v * 16 + sl] = o;
}

// ---------- L3 fused: out = log_softmax(mean(g[src]) + t), C=64 rows ----------
// 8 nodes/wave, 8 lanes/node; fixed predicated batches of 8.
__global__ __launch_bounds__(256) void k_gather8_lsm(const unsigned short* __restrict__ g,
                                                     const unsigned short* __restrict__ t,
                                                     const int* __restrict__ cnt,
                                                     const int* __restrict__ S,
                                                     const int* __restrict__ spillc,
                                                     const int* __restrict__ spill,
                                                     float* __restrict__ out) {
  const int tid = threadIdx.x;
  const int sl = tid & 7;
  const int v = blockIdx.x * 32 + (tid >> 3);
  const int deg = cnt[v];
  const int cap8 = deg < 8 ? deg : 8;
  const int cap16 = deg < 16 ? deg : 16;
  const int dcap = deg < 32 ? deg : 32;
  int idxA = (sl < cap8) ? S[v * 32 + sl] : 0;
  int idxB = (8 + sl < cap16) ? S[v * 32 + 8 + sl] : 0;
  const uint4* fp = (const uint4*)g;                // 8 uint4 per row

  float a0 = 0.f, a1 = 0.f, a2 = 0.f, a3 = 0.f, a4 = 0.f, a5 = 0.f, a6 = 0.f, a7 = 0.f;
  auto accum = [&](uint4 u) {
    a0 += bf2f_lo(u.x); a1 += bf2f_hi(u.x);
    a2 += bf2f_lo(u.y); a3 += bf2f_hi(u.y);
    a4 += bf2f_lo(u.z); a5 += bf2f_hi(u.z);
    a6 += bf2f_lo(u.w); a7 += bf2f_hi(u.w);
  };
  {
    uint4 u[8];
    #pragma unroll
    for (int e = 0; e < 8; e++) {
      int ie = __shfl(idxA, e, 8);
      u[e] = fp[(size_t)ie * 8 + sl];
    }
    #pragma unroll
    for (int e = 0; e < 8; e++) {
      if (e >= deg) { u[e].x = 0; u[e].y = 0; u[e].z = 0; u[e].w = 0; }
      accum(u[e]);
    }
  }
  if (deg > 8) {
    uint4 u[8];
    #pragma unroll
    for (int e = 0; e < 8; e++) {
      int ie = __shfl(idxB, e, 8);
      u[e] = fp[(size_t)ie * 8 + sl];
    }
    #pragma unroll
    for (int e = 0; e < 8; e++) {
      if (8 + e >= deg) { u[e].x = 0; u[e].y = 0; u[e].z = 0; u[e].w = 0; }
      accum(u[e]);
    }
  }
  for (int e = 16; e < dcap; e++) accum(fp[(size_t)S[v * 32 + e] * 8 + sl]);
  if (deg > 32) {                                    // never in practice
    int L = *spillc; if (L > SPILL_CAP) L = SPILL_CAP;
    for (int i2 = 0; i2 < L; i2++)
      if (spill[2 * i2] == v) accum(fp[(size_t)spill[2 * i2 + 1] * 8 + sl]);
  }

  float inv = 1.0f / (float)(deg > 1 ? deg : 1);
  uint4 tu = ((const uint4*)t)[(size_t)v * 8 + sl];
  float v0 = a0 * inv + bf2f_lo(tu.x), v1 = a1 * inv + bf2f_hi(tu.x);
  float v2 = a2 * inv + bf2f_lo(tu.y), v3 = a3 * inv + bf2f_hi(tu.y);
  float v4 = a4 * inv + bf2f_lo(tu.z), v5 = a5 * inv + bf2f_hi(tu.z);
  float v6 = a6 * inv + bf2f_lo(tu.w), v7 = a7 * inv + bf2f_hi(tu.w);
  float m = fmaxf(fmaxf(fmaxf(v0, v1), fmaxf(v2, v3)), fmaxf(fmaxf(v4, v5), fmaxf(v6, v7)));
  #pragma unroll
  for (int s = 4; s; s >>= 1) m = fmaxf(m, __shfl_xor(m, s, 8));
  float sum = expf(v0 - m) + expf(v1 - m) + expf(v2 - m) + expf(v3 - m)
            + expf(v4 - m) + expf(v5 - m) + expf(v6 - m) + expf(v7 - m);
  #pragma unroll
  for (int s = 4; s; s >>= 1) sum += __shfl_xor(sum, s, 8);
  float ls = m + logf(sum);
  float4* op = (float4*)out;
  op[(size_t)v * 16 + sl * 2 + 0] = make_float4(v0 - ls, v1 - ls, v2 - ls, v3 - ls);
  op[(size_t)v * 16 + sl * 2 + 1] = make_float4(v4 - ls, v5 - ls, v6 - ls, v7 - ls);
}

// ---------- bf16 MFMA GEMM, BK=64, XOR-swizzled LDS, coalesced repack epilogue ----------
template <int BN, bool DUAL>
__global__ __launch_bounds__(BN * 2) void k_gmm(
    const unsigned short* __restrict__ A1, const unsigned short* __restrict__ Wt1,
    const unsigned short* __restrict__ A2, const unsigned short* __restrict__ Wt2,
    const float* __restrict__ bias, int M, int K, int N,
    unsigned short* __restrict__ out1, unsigned short* __restrict__ out2, int relu) {
  constexpr int NWAVE = BN / 32;          // 4 or 2
  constexpr int ACHUNKS = 16;             // 128 rows / 8 rows-per-chunk
  constexpr int BCHUNKS = BN / 8;
  constexpr int STR = BN + 8;             // repack slab row stride
  __shared__ unsigned short smem[128 * 64 + BN * 64];
  unsigned short* As = smem;
  unsigned short* Bs = smem + 128 * 64;
  const int t = threadIdx.x;
  const int w = t >> 6, lane = t & 63;
  const int quad = lane >> 4, l15 = lane & 15;
  const int wm = w & 1, wn = w >> 1;      // BN=64: wn==0
  const int m0 = blockIdx.x * 128;
  const int n0 = DUAL ? blockIdx.y * BN : 0;
  const int srow = lane >> 3;             // row in 8-row chunk
  const int sk = (((lane & 7) ^ (srow & 7)) * 8);  // swizzled source k-offset (elems)

  const unsigned short* Wt = DUAL ? Wt1 : (blockIdx.y ? Wt2 : Wt1);
  unsigned short* out = DUAL ? out1 : (blockIdx.y ? out2 : out1);
  const float* bs = DUAL ? bias : (blockIdx.y ? bias : nullptr);

  f32x4 acc[4][4];
  #pragma unroll
  for (int i = 0; i < 4; i++)
    #pragma unroll
    for (int j = 0; j < 4; j++) acc[i][j] = (f32x4){0.f, 0.f, 0.f, 0.f};

  const int nph = DUAL ? 2 : 1;
  for (int ph = 0; ph < nph; ph++) {
    const unsigned short* A = (DUAL && ph) ? A2 : A1;
    const unsigned short* W = (DUAL && ph) ? Wt2 : Wt;
    for (int k0 = 0; k0 < K; k0 += 64) {
      #pragma unroll
      for (int c = w; c < ACHUNKS; c += NWAVE) {
        int rg = m0 + c * 8 + srow;
        if (rg >= M) rg = M - 1;          // clamp; epilogue guards stores
        async_cp16(A + (size_t)rg * K + k0 + sk, As + c * 512);
      }
      #pragma unroll
      for (int c = w; c < BCHUNKS; c += NWAVE) {
        async_cp16(W + (size_t)(n0 + c * 8 + srow) * K + k0 + sk, Bs + c * 512);
      }
      __syncthreads();
      short8 af[2][4], bfr[2][4];
      #pragma unroll
      for (int kh = 0; kh < 2; kh++) {
        #pragma unroll
        for (int mt = 0; mt < 4; mt++) {
          int r = wm * 64 + mt * 16 + l15;
          int cc = (kh * 4 + quad) ^ (r & 7);
          af[kh][mt] = *(const short8*)&As[r * 64 + cc * 8];
        }
        #pragma unroll
        for (int nt = 0; nt < 4; nt++) {
          int r = wn * 64 + nt * 16 + l15;
          int cc = (kh * 4 + quad) ^ (r & 7);
          bfr[kh][nt] = *(const short8*)&Bs[r * 64 + cc * 8];
        }
      }
      #pragma unroll
      for (int kh = 0; kh < 2; kh++)
        #pragma unroll
        for (int mt = 0; mt < 4; mt++)
          #pragma unroll
          for (int nt = 0; nt < 4; nt++)
            acc[mt][nt] = __builtin_amdgcn_mfma_f32_16x16x32_bf16(af[kh][mt], bfr[kh][nt], acc[mt][nt], 0, 0, 0);
      __syncthreads();
    }
  }

  // epilogue: repack per-mt slab (32 rows x BN cols bf16) in LDS -> 16B coalesced stores
  float bia[4];
  #pragma unroll
  for (int nt = 0; nt < 4; nt++)
    bia[nt] = bs ? bs[n0 + wn * 64 + nt * 16 + l15] : 0.f;
  constexpr int CH_PER_ROW = BN / 8;
  constexpr int TOT_CH = 32 * CH_PER_ROW;
  for (int mt = 0; mt < 4; mt++) {
    __syncthreads();
    #pragma unroll
    for (int nt = 0; nt < 4; nt++) {
      int col = wn * 64 + nt * 16 + l15;
      #pragma unroll
      for (int r = 0; r < 4; r++) {
        float v = acc[mt][nt][r] + bia[nt];
        if (relu) v = fmaxf(v, 0.f);
        smem[(wm * 16 + quad * 4 + r) * STR + col] = f2bf(v);
      }
    }
    __syncthreads();
    #pragma unroll
    for (int c = t; c < TOT_CH; c += BN * 2) {
      int row = c / CH_PER_ROW, ofs = (c % CH_PER_ROW) * 8;
      int m = m0 + (row >> 4) * 64 + mt * 16 + (row & 15);
      if (m < M)
        *(short8*)(out + (size_t)m * N + n0 + ofs) = *(const short8*)&smem[row * STR + ofs];
    }
  }
}

extern "C" void kernel_launch(void* const* d_in, const int* in_sizes, int n_in,
                              void* d_out, int out_size, void* d_ws, size_t ws_size,
                              hipStream_t stream) {
  const float* x   = (const float*)d_in[0];
  const int*   ei  = (const int*)d_in[1];
  const float* W1l = (const float*)d_in[2];
  const float* W1r = (const float*)d_in[3];
  const float* b1  = (const float*)d_in[4];
  const float* W2l = (const float*)d_in[5];
  const float* W2r = (const float*)d_in[6];
  const float* b2  = (const float*)d_in[7];
  const float* W3l = (const float*)d_in[8];
  const float* W3r = (const float*)d_in[9];
  const float* b3  = (const float*)d_in[10];
  float* out = (float*)d_out;
  const int* src = ei;
  const int* dst = ei + NE;

  char* w = (char*)d_ws;
  auto alloc = [&](size_t bytes) {
    char* p = w;
    w += (bytes + 255) & ~(size_t)255;
    return p;
  };
  int* cnt    = (int*)alloc((NN + 1) * sizeof(int));  // cnt[NN] + spillc at [NN]
  int* spillc = cnt + NN;
  int* S      = (int*)alloc((size_t)NN * 32 * sizeof(int));
  int* spill  = (int*)alloc(2 * SPILL_CAP * sizeof(int));
  unsigned short* xb = (unsigned short*)alloc((size_t)NN * 128 * 2);
  unsigned short* mb = (unsigned short*)alloc((size_t)NN * 128 * 2);  // L1 mean; aliased as g2
  unsigned short* h1 = (unsigned short*)alloc((size_t)NN * 256 * 2);  // aliased as g3|t3 later
  unsigned short* h2 = (unsigned short*)alloc((size_t)NN * 128 * 2);
  unsigned short* t2 = (unsigned short*)alloc((size_t)NN * 128 * 2);
  unsigned short* t1l = (unsigned short*)alloc(128 * 256 * 2);
  unsigned short* t1r = (unsigned short*)alloc(128 * 256 * 2);
  unsigned short* t2l = (unsigned short*)alloc(256 * 128 * 2);
  unsigned short* t2r = (unsigned short*)alloc(256 * 128 * 2);
  unsigned short* t3l = (unsigned short*)alloc(128 * 64 * 2);
  unsigned short* t3r = (unsigned short*)alloc(128 * 64 * 2);
  unsigned short* g2 = mb;                       // reuse: mb dead after L1 GEMM
  unsigned short* g3 = h1;                       // reuse: h1 dead after L2 GEMM
  unsigned short* t3 = h1 + (size_t)NN * 64;

  hipMemsetAsync(cnt, 0, (NN + 1) * sizeof(int), stream);
  // fused slot-CSR fill + cast + weight transpose (one dispatch, sections overlap)
  k_prep<<<6045, 256, 0, stream>>>(x, xb, W1l, W1r, W2l, W2r, W3l, W3r,
                                   t1l, t1r, t2l, t2r, t3l, t3r,
                                   src, dst, cnt, S, spillc, spill);

  const int MB = (NN + 127) / 128;  // 782
  const int GB16 = NN / 16;         // 6250
  const int GB32 = NN / 32;         // 3125
  // L1: h1 = relu(mean(xb)@W1l + xb@W1r + b1)
  k_gather4_128<false><<<GB16, 256, 0, stream>>>(xb, nullptr, cnt, S, spillc, spill, mb);
  k_gmm<128, true><<<dim3(MB, 2), 256, 0, stream>>>(mb, t1l, xb, t1r, b1, NN, 128, 256, h1, nullptr, 1);
  // L2: g2 = h1@W2l ; t2 = h1@W2r + b2 ; h2 = relu(mean(g2[src]) + t2)
  k_gmm<128, false><<<dim3(MB, 2), 256, 0, stream>>>(h1, t2l, nullptr, t2r, b2, NN, 256, 128, g2, t2, 0);
  k_gather4_128<true><<<GB16, 256, 0, stream>>>(g2, t2, cnt, S, spillc, spill, h2);
  // L3: g3 = h2@W3l ; t3 = h2@W3r + b3 ; out = log_softmax(mean(g3[src]) + t3)
  k_gmm<64, false><<<dim3(MB, 2), 128, 0, stream>>>(h2, t3l, nullptr, t3r, b3, NN, 128, 64, g3, t3, 0);
  k_gather8_lsm<<<GB32, 256, 0, stream>>>(g3, t3, cnt, S, spillc, spill, out);
}